// Round 6
// baseline (38.880 us; speedup 1.0000x reference)
//
#include <hip/hip_runtime.h>

// Chamfer via MFMA. B=4, N=M=8192, D=3, fp32.
// w(i,j) = q.t - 0.5|q|^2 - 0.5|t|^2 = -d^2/2; NN dist^2 = -2 * max_j w.
// Round-6 structure: each wave owns TWO 32-query i-tiles; B-tiles consumed in
// pairs -> per load-pair: 4 MFMA + 64 v_max3-lane-ops (2x arithmetic intensity
// vs round 5, which stalled on load latency / likely spills at 145 regs).
// Depth-1 pair prefetch only (+16 regs); peak ~118 VGPR < 128 cap of (256,4).
// NJ=4 j-chunks merged by atomicMax on order-encoded u32 (deterministic).
// bf16 hi/lo rep (validated rounds 3-5, absmax 0):
//   A(q) = [qh(3), ql(3), qh(3), hq_h, hq_l,  1,  1, 0,0,0]
//   B(t) = [th(3), th(3), tl(3),  -1,  -1, -ht_h, -ht_l, 0,0,0]

#define NPTS   8192
#define BATCH  4
#define NJ     4
#define JCHUNK (NPTS / NJ)         // 2048
#define JTILES (JCHUNK / 32)       // 64
#define NSLOTS (2 * BATCH * NPTS)  // 65536
#define REPPAD 4096                // over-read pad (prefetch beyond last tile)

typedef __attribute__((ext_vector_type(8))) short short8v;
typedef __attribute__((ext_vector_type(16))) float f32x16;

__device__ __forceinline__ unsigned enc_f32(float f) {
  unsigned u = __float_as_uint(f);
  return (u & 0x80000000u) ? ~u : (u | 0x80000000u);
}
__device__ __forceinline__ float dec_f32(unsigned u) {
  u = (u & 0x80000000u) ? (u ^ 0x80000000u) : ~u;
  return __uint_as_float(u);
}
__device__ __forceinline__ unsigned short f2bf(float x) {   // RNE bf16
  unsigned u = __float_as_uint(x);
  unsigned r = u + 0x7FFFu + ((u >> 16) & 1u);
  return (unsigned short)(r >> 16);
}
__device__ __forceinline__ float bf2f(unsigned short b) {
  return __uint_as_float((unsigned)b << 16);
}

__global__ __launch_bounds__(256) void prep(
    const float* __restrict__ c1, const float* __restrict__ c2,
    unsigned short* __restrict__ a1, unsigned short* __restrict__ a2,
    unsigned short* __restrict__ b1, unsigned short* __restrict__ b2,
    unsigned* __restrict__ rowbuf) {
  int pid = blockIdx.x * 256 + threadIdx.x;
  if (pid >= BATCH * NPTS) return;
  rowbuf[pid] = 0u;                    // below enc of any real float
  rowbuf[pid + BATCH * NPTS] = 0u;
  const unsigned short one = 0x3F80u, negone = 0xBF80u;
  const float* cs[2] = {c1, c2};
  unsigned short* as[2] = {a1, a2};
  unsigned short* bs[2] = {b1, b2};
  #pragma unroll
  for (int c = 0; c < 2; ++c) {
    float x = cs[c][pid * 3 + 0], y = cs[c][pid * 3 + 1], z = cs[c][pid * 3 + 2];
    unsigned short xh = f2bf(x), yh = f2bf(y), zh = f2bf(z);
    unsigned short xl = f2bf(x - bf2f(xh)), yl = f2bf(y - bf2f(yh)),
                   zl = f2bf(z - bf2f(zh));
    float hn = 0.5f * (x * x + y * y + z * z);
    unsigned short hh = f2bf(hn), hl = f2bf(hn - bf2f(hh));
    unsigned short va[16] = {xh, yh, zh, xl, yl, zl, xh, yh, zh,
                             hh, hl, one, one, 0, 0, 0};
    unsigned short nh = hh ^ 0x8000u, nl = hl ^ 0x8000u;
    unsigned short vb[16] = {xh, yh, zh, xh, yh, zh, xl, yl, zl,
                             negone, negone, nh, nl, 0, 0, 0};
    uint4* da = (uint4*)(as[c] + (size_t)pid * 16);
    da[0] = *(const uint4*)&va[0];
    da[1] = *(const uint4*)&va[8];
    uint4* db = (uint4*)(bs[c] + (size_t)pid * 16);
    db[0] = *(const uint4*)&vb[0];
    db[1] = *(const uint4*)&vb[8];
  }
}

// grid = 2(dir) x 4(b) x 32(iblk) x 4(jc) = 1024 blocks x 4 waves.
// Wave owns i-tiles at iblk*256 + wave*64 (+0, +32); loops 64 target tiles
// as 32 pairs with depth-1 pair prefetch.
__global__ __launch_bounds__(256, 4) void chamfer_mfma(
    const unsigned short* __restrict__ a1, const unsigned short* __restrict__ a2,
    const unsigned short* __restrict__ b1, const unsigned short* __restrict__ b2,
    unsigned* __restrict__ rowbuf) {
  int bid  = blockIdx.x;
  int jc   = bid & (NJ - 1);
  int iblk = (bid >> 2) & 31;
  int b    = (bid >> 7) & 3;
  int dir  = bid >> 9;

  const unsigned short* A = dir ? a2 : a1;   // queries
  const unsigned short* B = dir ? b1 : b2;   // targets

  int wave = threadIdx.x >> 6;
  int lane = threadIdx.x & 63;
  int i0 = iblk * 256 + wave * 64;           // first of two i-tiles
  int j0 = jc * JCHUNK;

  const unsigned short* Abase =
      A + ((size_t)b * NPTS + i0 + (lane & 31)) * 16 + (lane >> 5) * 8;
  short8v af0 = *(const short8v*)(const void*)(Abase);
  short8v af1 = *(const short8v*)(const void*)(Abase + 32 * 16);

  const short8v* Bp = (const short8v*)(const void*)(
      B + ((size_t)b * NPTS + j0 + (lane & 31)) * 16 + (lane >> 5) * 8);
  // one 32-point B-tile = 64 short8v per lane-stride view

  f32x16 zero;
  #pragma unroll
  for (int i = 0; i < 16; ++i) zero[i] = 0.0f;
  f32x16 mrow0, mrow1;
  #pragma unroll
  for (int i = 0; i < 16; ++i) { mrow0[i] = -3.4e38f; mrow1[i] = -3.4e38f; }

#define LD(jt) Bp[(size_t)(jt) * 64]

  short8v u0 = LD(0), u1 = LD(1);
  for (int jt = 0; jt < JTILES; jt += 2) {
    short8v n0 = LD(jt + 2);                 // over-reads 2 tiles at the end
    short8v n1 = LD(jt + 3);                 // (REPPAD covers it; never used)
    {
      f32x16 accA = __builtin_amdgcn_mfma_f32_32x32x16_bf16(af0, u0, zero, 0, 0, 0);
      f32x16 accB = __builtin_amdgcn_mfma_f32_32x32x16_bf16(af0, u1, zero, 0, 0, 0);
      #pragma unroll
      for (int r = 0; r < 16; ++r)
        mrow0[r] = fmaxf(fmaxf(accA[r], accB[r]), mrow0[r]);   // v_max3
    }
    {
      f32x16 accA = __builtin_amdgcn_mfma_f32_32x32x16_bf16(af1, u0, zero, 0, 0, 0);
      f32x16 accB = __builtin_amdgcn_mfma_f32_32x32x16_bf16(af1, u1, zero, 0, 0, 0);
      #pragma unroll
      for (int r = 0; r < 16; ++r)
        mrow1[r] = fmaxf(fmaxf(accA[r], accB[r]), mrow1[r]);   // v_max3
    }
    u0 = n0; u1 = n1;
  }
#undef LD

  // reduce over the 32 columns held across lanes of each half
  #pragma unroll
  for (int r = 0; r < 16; ++r) {
    float v0 = mrow0[r], v1 = mrow1[r];
    #pragma unroll
    for (int sh = 1; sh <= 16; sh <<= 1) {
      v0 = fmaxf(v0, __shfl_xor(v0, sh, 64));
      v1 = fmaxf(v1, __shfl_xor(v1, sh, 64));
    }
    mrow0[r] = v0; mrow1[r] = v1;
  }
  if ((lane & 31) == 0) {
    int half = lane >> 5;
    unsigned* rb = rowbuf + ((size_t)dir * BATCH + b) * NPTS + i0;
    #pragma unroll
    for (int r = 0; r < 16; ++r) {
      int row = (r & 3) + 8 * (r >> 2) + 4 * half;   // verified 32x32 C/D map
      atomicMax(rb + row, enc_f32(mrow0[r]));        // NJ=4 contenders
      atomicMax(rb + 32 + row, enc_f32(mrow1[r]));
    }
  }
}

__global__ __launch_bounds__(1024) void loss_final(
    const unsigned* __restrict__ rowbuf, float* __restrict__ out) {
  int tid = threadIdx.x;
  const uint4* rb4 = (const uint4*)rowbuf;   // 16384 uint4
  float s = 0.0f;
  #pragma unroll
  for (int k = 0; k < NSLOTS / 4096; ++k) {  // 16 iters
    uint4 u = rb4[k * 1024 + tid];
    s = fmaf(-2.0f, dec_f32(u.x), s);
    s = fmaf(-2.0f, dec_f32(u.y), s);
    s = fmaf(-2.0f, dec_f32(u.z), s);
    s = fmaf(-2.0f, dec_f32(u.w), s);
  }
  #pragma unroll
  for (int off = 32; off > 0; off >>= 1) s += __shfl_down(s, off, 64);
  __shared__ float wsum[16];
  if ((tid & 63) == 0) wsum[tid >> 6] = s;
  __syncthreads();
  if (tid == 0) {
    float t = 0.0f;
    #pragma unroll
    for (int w2 = 0; w2 < 16; ++w2) t += wsum[w2];
    out[0] = t;
  }
}

extern "C" void kernel_launch(void* const* d_in, const int* in_sizes, int n_in,
                              void* d_out, int out_size, void* d_ws, size_t ws_size,
                              hipStream_t stream) {
  const float* c1 = (const float*)d_in[0];
  const float* c2 = (const float*)d_in[1];
  float* out = (float*)d_out;

  char* ws = (char*)d_ws;
  unsigned* rowbuf = (unsigned*)ws;                          // 65536 u32 = 256 KB
  unsigned short* a1 = (unsigned short*)(ws + (size_t)NSLOTS * 4);
  unsigned short* a2 = a1 + (size_t)BATCH * NPTS * 16;       // 1 MB each
  unsigned short* b1 = a2 + (size_t)BATCH * NPTS * 16;
  unsigned short* b2 = b1 + (size_t)BATCH * NPTS * 16 + REPPAD / 2;

  prep<<<(BATCH * NPTS) / 256, 256, 0, stream>>>(c1, c2, a1, a2, b1, b2, rowbuf);
  chamfer_mfma<<<2 * BATCH * 32 * NJ, 256, 0, stream>>>(a1, a2, b1, b2, rowbuf);
  loss_final<<<1, 1024, 0, stream>>>(rowbuf, out);
}